// Round 1
// baseline (3872.507 us; speedup 1.0000x reference)
//
#include <hip/hip_runtime.h>
#include <cmath>

#define NL 16
#define TBL (1u << 19)
#define HID 64

struct Res16 { float r[NL]; };

__global__ __launch_bounds__(256) void nerf_fused(
    const float* __restrict__ x,
    const float* __restrict__ dvec,
    const int*   __restrict__ app_idx,
    const float* __restrict__ ht,
    const float* __restrict__ app_table,
    const float* __restrict__ sw0, const float* __restrict__ sb0,
    const float* __restrict__ sw1, const float* __restrict__ sb1,
    const float* __restrict__ cw0, const float* __restrict__ cb0,
    const float* __restrict__ cw1, const float* __restrict__ cb1,
    const float* __restrict__ cw2, const float* __restrict__ cb2,
    float* __restrict__ out, Res16 rt, int n_pts)
{
    int n = blockIdx.x * blockDim.x + threadIdx.x;
    if (n >= n_pts) return;

    float px = (x[3*n+0] + 1.f) * 0.5f;
    float py = (x[3*n+1] + 1.f) * 0.5f;
    float pz = (x[3*n+2] + 1.f) * 0.5f;

    // ---- hash encode fused into first density layer: h = sb0 + enc @ sw0 ----
    float h[HID];
    #pragma unroll
    for (int o = 0; o < HID; o++) h[o] = sb0[o];

    #pragma unroll
    for (int l = 0; l < NL; l++) {
        float res = rt.r[l];
        float xs = px * res, ys = py * res, zs = pz * res;
        float fx = floorf(xs), fy = floorf(ys), fz = floorf(zs);
        float wx = xs - fx, wy = ys - fy, wz = zs - fz;
        float ax = 1.f - wx, ay = 1.f - wy, az = 1.f - wz;
        unsigned X = (unsigned)fx, Y = (unsigned)fy, Z = (unsigned)fz;
        unsigned hx0 = X;                     unsigned hx1 = hx0 + 1u;
        unsigned hy0 = Y * 2654435761u;       unsigned hy1 = hy0 + 2654435761u;
        unsigned hz0 = Z * 805459861u;        unsigned hz1 = hz0 + 805459861u;
        const float2* base = reinterpret_cast<const float2*>(ht) + (size_t)l * TBL;

        float e0 = 0.f, e1 = 0.f;
        #pragma unroll
        for (int c = 0; c < 8; c++) {
            unsigned idx = (((c & 4) ? hx1 : hx0) ^
                            ((c & 2) ? hy1 : hy0) ^
                            ((c & 1) ? hz1 : hz0)) & (TBL - 1u);
            float2 f = base[idx];
            float wgt = ((c & 4) ? wx : ax) * ((c & 2) ? wy : ay) * ((c & 1) ? wz : az);
            e0 += wgt * f.x;
            e1 += wgt * f.y;
        }
        const float* r0 = sw0 + (2 * l) * HID;
        #pragma unroll
        for (int o = 0; o < HID; o++) h[o] += e0 * r0[o] + e1 * r0[HID + o];
    }
    #pragma unroll
    for (int o = 0; o < HID; o++) h[o] = fmaxf(h[o], 0.f);

    // ---- density layer 2: h1[16] = h @ sw1 + sb1 ----
    float h1[16];
    #pragma unroll
    for (int o = 0; o < 16; o++) h1[o] = sb1[o];
    #pragma unroll
    for (int i = 0; i < HID; i++) {
        float v = h[i];
        const float* wr = sw1 + i * 16;
        #pragma unroll
        for (int o = 0; o < 16; o++) h1[o] += v * wr[o];
    }

    float z100 = 100.f * h1[0];
    float sigma = (z100 > 20.f) ? h1[0] : (log1pf(expf(z100)) * 0.01f);

    // ---- SH16 of normalized direction ----
    float dx = dvec[3*n+0], dy = dvec[3*n+1], dz = dvec[3*n+2];
    float invn = 1.0f / sqrtf(dx*dx + dy*dy + dz*dz);
    dx *= invn; dy *= invn; dz *= invn;
    float xx = dx*dx, yy = dy*dy, zz = dz*dz;
    float xy = dx*dy, yz = dy*dz, xz = dx*dz;
    float sh[16];
    sh[0]  = 0.28209479177387814f;
    sh[1]  = -0.48860251190291987f * dy;
    sh[2]  =  0.48860251190291987f * dz;
    sh[3]  = -0.48860251190291987f * dx;
    sh[4]  =  1.0925484305920792f * xy;
    sh[5]  = -1.0925484305920792f * yz;
    sh[6]  =  0.94617469575756f * zz - 0.31539156525252005f;
    sh[7]  = -1.0925484305920792f * xz;
    sh[8]  =  0.5462742152960396f * (xx - yy);
    sh[9]  = -0.5900435899266435f * dy * (3.f * xx - yy);
    sh[10] =  2.890611442640554f * xy * dz;
    sh[11] = -0.4570457994644657f * dy * (4.f * zz - xx - yy);
    sh[12] =  0.37317633259011546f * dz * (2.f * zz - 3.f * xx - 3.f * yy);
    sh[13] = -0.4570457994644657f * dx * (4.f * zz - xx - yy);
    sh[14] =  1.445305721320277f * dz * (xx - yy);
    sh[15] = -0.5900435899266435f * dx * (xx - 3.f * yy);

    // ---- color layer 0: c1 = relu([geo, sh, app] @ cw0 + cb0) ----
    float c1[HID];
    #pragma unroll
    for (int o = 0; o < HID; o++) c1[o] = cb0[o];
    #pragma unroll
    for (int i = 0; i < 15; i++) {
        float v = h1[i + 1];
        const float* wr = cw0 + i * HID;
        #pragma unroll
        for (int o = 0; o < HID; o++) c1[o] += v * wr[o];
    }
    #pragma unroll
    for (int i = 0; i < 16; i++) {
        float v = sh[i];
        const float* wr = cw0 + (15 + i) * HID;
        #pragma unroll
        for (int o = 0; o < HID; o++) c1[o] += v * wr[o];
    }
    {
        const float4* arow = reinterpret_cast<const float4*>(app_table + (size_t)app_idx[n] * 48);
        for (int j4 = 0; j4 < 12; j4++) {   // rolled: activations come from memory
            float4 v = arow[j4];
            const float* wr = cw0 + (31 + 4 * j4) * HID;
            #pragma unroll
            for (int o = 0; o < HID; o++) c1[o] += v.x * wr[o];
            #pragma unroll
            for (int o = 0; o < HID; o++) c1[o] += v.y * wr[HID + o];
            #pragma unroll
            for (int o = 0; o < HID; o++) c1[o] += v.z * wr[2 * HID + o];
            #pragma unroll
            for (int o = 0; o < HID; o++) c1[o] += v.w * wr[3 * HID + o];
        }
    }
    #pragma unroll
    for (int o = 0; o < HID; o++) c1[o] = fmaxf(c1[o], 0.f);

    // ---- color layer 1: c2 = relu(c1 @ cw1 + cb1) ----
    float c2[HID];
    #pragma unroll
    for (int o = 0; o < HID; o++) c2[o] = cb1[o];
    #pragma unroll
    for (int i = 0; i < HID; i++) {
        float v = c1[i];
        const float* wr = cw1 + i * HID;
        #pragma unroll
        for (int o = 0; o < HID; o++) c2[o] += v * wr[o];
    }
    #pragma unroll
    for (int o = 0; o < HID; o++) c2[o] = fmaxf(c2[o], 0.f);

    // ---- color layer 2: rgb = sigmoid(c2 @ cw2 + cb2) ----
    float r = cb2[0], g = cb2[1], b = cb2[2];
    #pragma unroll
    for (int i = 0; i < HID; i++) {
        float v = c2[i];
        r += v * cw2[i * 3 + 0];
        g += v * cw2[i * 3 + 1];
        b += v * cw2[i * 3 + 2];
    }
    r = 1.f / (1.f + expf(-r));
    g = 1.f / (1.f + expf(-g));
    b = 1.f / (1.f + expf(-b));

    reinterpret_cast<float4*>(out)[n] = make_float4(sigma, r, g, b);
}

extern "C" void kernel_launch(void* const* d_in, const int* in_sizes, int n_in,
                              void* d_out, int out_size, void* d_ws, size_t ws_size,
                              hipStream_t stream) {
    const float* x         = (const float*)d_in[0];
    const float* dvec      = (const float*)d_in[1];
    const int*   app_idx   = (const int*)  d_in[2];
    const float* ht        = (const float*)d_in[3];
    const float* app_table = (const float*)d_in[4];
    const float* sw0 = (const float*)d_in[5];
    const float* sb0 = (const float*)d_in[6];
    const float* sw1 = (const float*)d_in[7];
    const float* sb1 = (const float*)d_in[8];
    const float* cw0 = (const float*)d_in[9];
    const float* cb0 = (const float*)d_in[10];
    const float* cw1 = (const float*)d_in[11];
    const float* cb1 = (const float*)d_in[12];
    const float* cw2 = (const float*)d_in[13];
    const float* cb2 = (const float*)d_in[14];

    int n_pts = in_sizes[0] / 3;

    // RES table computed in double precision, mirroring numpy exactly.
    Res16 rt;
    double bb = exp(log(2048.0 / 16.0) / 15.0);
    for (int l = 0; l < NL; l++) rt.r[l] = (float)floor(16.0 * pow(bb, (double)l));

    dim3 grid((n_pts + 255) / 256), block(256);
    hipLaunchKernelGGL(nerf_fused, grid, block, 0, stream,
                       x, dvec, app_idx, ht, app_table,
                       sw0, sb0, sw1, sb1, cw0, cb0, cw1, cb1, cw2, cb2,
                       (float*)d_out, rt, n_pts);
}

// Round 3
// 3296.146 us; speedup vs baseline: 1.1749x; 1.1749x over previous
//
#include <hip/hip_runtime.h>
#include <cmath>
#include <type_traits>

#define NL 16
#define TBL_N (1u << 19)
#define HID 64

struct Res16 { float r[NL]; };

__device__ __forceinline__ unsigned short f2bf(float f) {
    unsigned u = __float_as_uint(f);
    unsigned r = (u + 0x7FFFu + ((u >> 16) & 1u)) >> 16;   // RNE
    return (unsigned short)r;
}

// corner payload -> (f0, f1)
__device__ __forceinline__ void corner_vals(unsigned v, float& f0, float& f1) {
    f0 = __uint_as_float(v << 16);
    f1 = __uint_as_float(v & 0xffff0000u);
}
__device__ __forceinline__ void corner_vals(float2 v, float& f0, float& f1) {
    f0 = v.x; f1 = v.y;
}

__global__ __launch_bounds__(256) void repack_bf16(const float2* __restrict__ src,
                                                   unsigned* __restrict__ dst, int n) {
    int i = blockIdx.x * blockDim.x + threadIdx.x;
    if (i >= n) return;
    float2 v = src[i];
    dst[i] = (unsigned)f2bf(v.x) | ((unsigned)f2bf(v.y) << 16);
}

template <int USE_BF16>
__global__ __launch_bounds__(256) void nerf_fused(
    const float* __restrict__ x,
    const float* __restrict__ dvec,
    const int*   __restrict__ app_idx,
    const void*  __restrict__ tbl_raw,
    const float* __restrict__ app_table,
    const float* __restrict__ sw0, const float* __restrict__ sb0,
    const float* __restrict__ sw1, const float* __restrict__ sb1,
    const float* __restrict__ cw0, const float* __restrict__ cb0,
    const float* __restrict__ cw1, const float* __restrict__ cb1,
    const float* __restrict__ cw2, const float* __restrict__ cb2,
    float* __restrict__ out, Res16 rt, int n_pts)
{
    using CT = typename std::conditional<USE_BF16 != 0, unsigned, float2>::type;
    const CT* __restrict__ tbl = (const CT*)tbl_raw;

    int n = blockIdx.x * blockDim.x + threadIdx.x;
    if (n >= n_pts) return;

    float px = (x[3*n+0] + 1.f) * 0.5f;
    float py = (x[3*n+1] + 1.f) * 0.5f;
    float pz = (x[3*n+2] + 1.f) * 0.5f;

    // ================= Phase A: hash gather with 3-deep software pipeline ===
    float e[2*NL];
    CT    fb[3][8];     // in-flight corner payloads (static-indexed: unrolled)
    float lw[3][3];     // in-flight trilinear weights

#define ISSUE(l, s) do {                                                        \
    float res = rt.r[(l)];                                                      \
    float xs = px*res, ys = py*res, zs = pz*res;                                \
    float fx = floorf(xs), fy = floorf(ys), fz = floorf(zs);                    \
    lw[(s)][0] = xs - fx; lw[(s)][1] = ys - fy; lw[(s)][2] = zs - fz;           \
    unsigned X = (unsigned)fx, Y = (unsigned)fy, Z = (unsigned)fz;              \
    unsigned hx0 = X,               hx1 = X + 1u;                               \
    unsigned hy0 = Y * 2654435761u, hy1 = hy0 + 2654435761u;                    \
    unsigned hz0 = Z * 805459861u,  hz1 = hz0 + 805459861u;                     \
    const CT* base = tbl + (size_t)(l) * TBL_N;                                 \
    _Pragma("unroll")                                                           \
    for (int c = 0; c < 8; c++) {                                               \
        unsigned idx = (((c & 4) ? hx1 : hx0) ^                                 \
                        ((c & 2) ? hy1 : hy0) ^                                 \
                        ((c & 1) ? hz1 : hz0)) & (TBL_N - 1u);                  \
        fb[(s)][c] = base[idx];                                                 \
    }                                                                           \
} while (0)

#define CONSUME(l, s) do {                                                      \
    float wx = lw[(s)][0], wy = lw[(s)][1], wz = lw[(s)][2];                    \
    float ax = 1.f - wx, ay = 1.f - wy, az = 1.f - wz;                          \
    float e0 = 0.f, e1 = 0.f;                                                   \
    _Pragma("unroll")                                                           \
    for (int c = 0; c < 8; c++) {                                               \
        float f0, f1;                                                           \
        corner_vals(fb[(s)][c], f0, f1);                                        \
        float wgt = ((c & 4) ? wx : ax) * ((c & 2) ? wy : ay)                   \
                  * ((c & 1) ? wz : az);                                        \
        e0 += wgt * f0;                                                         \
        e1 += wgt * f1;                                                         \
    }                                                                           \
    e[2*(l)]   = e0;                                                            \
    e[2*(l)+1] = e1;                                                            \
} while (0)

    ISSUE(0, 0); ISSUE(1, 1); ISSUE(2, 2);
    #pragma unroll
    for (int l = 0; l < NL; l++) {
        CONSUME(l, l % 3);
        if (l + 3 < NL) ISSUE(l + 3, (l + 3) % 3);
    }
#undef ISSUE
#undef CONSUME

    // ================= Phase B: density MLP =================================
    float h[HID];
    #pragma unroll
    for (int o = 0; o < HID; o++) h[o] = sb0[o];
    #pragma unroll
    for (int l = 0; l < NL; l++) {
        const float* r0 = sw0 + (2 * l) * HID;
        float e0 = e[2*l], e1 = e[2*l+1];
        #pragma unroll
        for (int o = 0; o < HID; o++) h[o] += e0 * r0[o] + e1 * r0[HID + o];
    }
    #pragma unroll
    for (int o = 0; o < HID; o++) h[o] = fmaxf(h[o], 0.f);

    float h1[16];
    #pragma unroll
    for (int o = 0; o < 16; o++) h1[o] = sb1[o];
    #pragma unroll
    for (int i = 0; i < HID; i++) {
        float v = h[i];
        const float* wr = sw1 + i * 16;
        #pragma unroll
        for (int o = 0; o < 16; o++) h1[o] += v * wr[o];
    }

    float z100 = 100.f * h1[0];
    float sigma = (z100 > 20.f) ? h1[0] : (log1pf(expf(z100)) * 0.01f);

    // ================= SH16 =================================================
    float dx = dvec[3*n+0], dy = dvec[3*n+1], dz = dvec[3*n+2];
    float invn = 1.0f / sqrtf(dx*dx + dy*dy + dz*dz);
    dx *= invn; dy *= invn; dz *= invn;
    float xx = dx*dx, yy = dy*dy, zz = dz*dz;
    float xy = dx*dy, yz = dy*dz, xz = dx*dz;
    float sh[16];
    sh[0]  = 0.28209479177387814f;
    sh[1]  = -0.48860251190291987f * dy;
    sh[2]  =  0.48860251190291987f * dz;
    sh[3]  = -0.48860251190291987f * dx;
    sh[4]  =  1.0925484305920792f * xy;
    sh[5]  = -1.0925484305920792f * yz;
    sh[6]  =  0.94617469575756f * zz - 0.31539156525252005f;
    sh[7]  = -1.0925484305920792f * xz;
    sh[8]  =  0.5462742152960396f * (xx - yy);
    sh[9]  = -0.5900435899266435f * dy * (3.f * xx - yy);
    sh[10] =  2.890611442640554f * xy * dz;
    sh[11] = -0.4570457994644657f * dy * (4.f * zz - xx - yy);
    sh[12] =  0.37317633259011546f * dz * (2.f * zz - 3.f * xx - 3.f * yy);
    sh[13] = -0.4570457994644657f * dx * (4.f * zz - xx - yy);
    sh[14] =  1.445305721320277f * dz * (xx - yy);
    sh[15] = -0.5900435899266435f * dx * (xx - 3.f * yy);

    // ================= color MLP ============================================
    float c1[HID];
    #pragma unroll
    for (int o = 0; o < HID; o++) c1[o] = cb0[o];
    #pragma unroll
    for (int i = 0; i < 15; i++) {
        float v = h1[i + 1];
        const float* wr = cw0 + i * HID;
        #pragma unroll
        for (int o = 0; o < HID; o++) c1[o] += v * wr[o];
    }
    #pragma unroll
    for (int i = 0; i < 16; i++) {
        float v = sh[i];
        const float* wr = cw0 + (15 + i) * HID;
        #pragma unroll
        for (int o = 0; o < HID; o++) c1[o] += v * wr[o];
    }
    {
        const float4* arow = reinterpret_cast<const float4*>(app_table + (size_t)app_idx[n] * 48);
        for (int j4 = 0; j4 < 12; j4++) {
            float4 v = arow[j4];
            const float* wr = cw0 + (31 + 4 * j4) * HID;
            #pragma unroll
            for (int o = 0; o < HID; o++) c1[o] += v.x * wr[o];
            #pragma unroll
            for (int o = 0; o < HID; o++) c1[o] += v.y * wr[HID + o];
            #pragma unroll
            for (int o = 0; o < HID; o++) c1[o] += v.z * wr[2 * HID + o];
            #pragma unroll
            for (int o = 0; o < HID; o++) c1[o] += v.w * wr[3 * HID + o];
        }
    }
    #pragma unroll
    for (int o = 0; o < HID; o++) c1[o] = fmaxf(c1[o], 0.f);

    float c2[HID];
    #pragma unroll
    for (int o = 0; o < HID; o++) c2[o] = cb1[o];
    #pragma unroll
    for (int i = 0; i < HID; i++) {
        float v = c1[i];
        const float* wr = cw1 + i * HID;
        #pragma unroll
        for (int o = 0; o < HID; o++) c2[o] += v * wr[o];
    }
    #pragma unroll
    for (int o = 0; o < HID; o++) c2[o] = fmaxf(c2[o], 0.f);

    float r = cb2[0], g = cb2[1], b = cb2[2];
    #pragma unroll
    for (int i = 0; i < HID; i++) {
        float v = c2[i];
        r += v * cw2[i * 3 + 0];
        g += v * cw2[i * 3 + 1];
        b += v * cw2[i * 3 + 2];
    }
    r = 1.f / (1.f + expf(-r));
    g = 1.f / (1.f + expf(-g));
    b = 1.f / (1.f + expf(-b));

    reinterpret_cast<float4*>(out)[n] = make_float4(sigma, r, g, b);
}

extern "C" void kernel_launch(void* const* d_in, const int* in_sizes, int n_in,
                              void* d_out, int out_size, void* d_ws, size_t ws_size,
                              hipStream_t stream) {
    const float* x         = (const float*)d_in[0];
    const float* dvec      = (const float*)d_in[1];
    const int*   app_idx   = (const int*)  d_in[2];
    const float* ht        = (const float*)d_in[3];
    const float* app_table = (const float*)d_in[4];
    const float* sw0 = (const float*)d_in[5];
    const float* sb0 = (const float*)d_in[6];
    const float* sw1 = (const float*)d_in[7];
    const float* sb1 = (const float*)d_in[8];
    const float* cw0 = (const float*)d_in[9];
    const float* cb0 = (const float*)d_in[10];
    const float* cw1 = (const float*)d_in[11];
    const float* cb1 = (const float*)d_in[12];
    const float* cw2 = (const float*)d_in[13];
    const float* cb2 = (const float*)d_in[14];

    int n_pts = in_sizes[0] / 3;

    Res16 rt;
    double bb = exp(log(2048.0 / 16.0) / 15.0);
    for (int l = 0; l < NL; l++) rt.r[l] = (float)floor(16.0 * pow(bb, (double)l));

    dim3 grid((n_pts + 255) / 256), block(256);

    const size_t tbl_entries = (size_t)NL * TBL_N;              // 8.39M entries
    const bool use_bf16 = ws_size >= tbl_entries * sizeof(unsigned);  // 32 MiB

    if (use_bf16) {
        int nent = (int)tbl_entries;
        hipLaunchKernelGGL(repack_bf16, dim3((nent + 255) / 256), dim3(256), 0, stream,
                           (const float2*)ht, (unsigned*)d_ws, nent);
        hipLaunchKernelGGL((nerf_fused<1>), grid, block, 0, stream,
                           x, dvec, app_idx, (const void*)d_ws, app_table,
                           sw0, sb0, sw1, sb1, cw0, cb0, cw1, cb1, cw2, cb2,
                           (float*)d_out, rt, n_pts);
    } else {
        hipLaunchKernelGGL((nerf_fused<0>), grid, block, 0, stream,
                           x, dvec, app_idx, (const void*)ht, app_table,
                           sw0, sb0, sw1, sb1, cw0, cb0, cw1, cb1, cw2, cb2,
                           (float*)d_out, rt, n_pts);
    }
}

// Round 4
// 2280.399 us; speedup vs baseline: 1.6982x; 1.4454x over previous
//
#include <hip/hip_runtime.h>
#include <cmath>
#include <type_traits>

#define NL 16
#define TBL_N (1u << 19)
#define HID 64

struct Res16 { float r[NL]; };

__device__ __forceinline__ unsigned short f2bf(float f) {
    unsigned u = __float_as_uint(f);
    unsigned r = (u + 0x7FFFu + ((u >> 16) & 1u)) >> 16;   // RNE
    return (unsigned short)r;
}
__device__ __forceinline__ unsigned pack_bf(float a, float b) {
    return (unsigned)f2bf(a) | ((unsigned)f2bf(b) << 16);
}
// corner payload -> (f0, f1)
__device__ __forceinline__ void corner_vals(unsigned v, float& f0, float& f1) {
    f0 = __uint_as_float(v << 16);
    f1 = __uint_as_float(v & 0xffff0000u);
}
__device__ __forceinline__ void corner_vals(float2 v, float& f0, float& f1) {
    f0 = v.x; f1 = v.y;
}

__global__ __launch_bounds__(256) void repack_bf16(const float2* __restrict__ src,
                                                   unsigned* __restrict__ dst, int n) {
    int i = blockIdx.x * blockDim.x + threadIdx.x;
    if (i >= n) return;
    float2 v = src[i];
    dst[i] = pack_bf(v.x, v.y);
}

// ======================= Kernel E: hash-grid encode ========================
// Lean register footprint -> high occupancy -> latency hidden by TLP.
// enc layout transposed: enc[l*P + p] (coalesced dword per level).
__global__ __launch_bounds__(256) void nerf_encode(
    const float* __restrict__ x,
    const unsigned* __restrict__ tbl,     // bf16-packed hash table
    unsigned* __restrict__ enc,
    Res16 rt, int p0, int P, int n_pts)
{
    int p = blockIdx.x * blockDim.x + threadIdx.x;
    if (p >= P) return;
    int n = p0 + p;
    if (n >= n_pts) return;

    float px = (x[3*n+0] + 1.f) * 0.5f;
    float py = (x[3*n+1] + 1.f) * 0.5f;
    float pz = (x[3*n+2] + 1.f) * 0.5f;

    #pragma unroll 4
    for (int l = 0; l < NL; l++) {
        float res = rt.r[l];
        float xs = px*res, ys = py*res, zs = pz*res;
        float fx = floorf(xs), fy = floorf(ys), fz = floorf(zs);
        float wx = xs - fx, wy = ys - fy, wz = zs - fz;
        float ax = 1.f - wx, ay = 1.f - wy, az = 1.f - wz;
        unsigned X = (unsigned)fx, Y = (unsigned)fy, Z = (unsigned)fz;
        unsigned hx0 = X,               hx1 = X + 1u;
        unsigned hy0 = Y * 2654435761u, hy1 = hy0 + 2654435761u;
        unsigned hz0 = Z * 805459861u,  hz1 = hz0 + 805459861u;
        const unsigned* base = tbl + (size_t)l * TBL_N;

        float e0 = 0.f, e1 = 0.f;
        #pragma unroll
        for (int c = 0; c < 8; c++) {
            unsigned idx = (((c & 4) ? hx1 : hx0) ^
                            ((c & 2) ? hy1 : hy0) ^
                            ((c & 1) ? hz1 : hz0)) & (TBL_N - 1u);
            unsigned v = base[idx];
            float f0, f1;
            corner_vals(v, f0, f1);
            float wgt = ((c & 4) ? wx : ax) * ((c & 2) ? wy : ay) * ((c & 1) ? wz : az);
            e0 += wgt * f0;
            e1 += wgt * f1;
        }
        enc[(size_t)l * P + p] = pack_bf(e0, e1);
    }
}

// ======================= Kernel M: MLPs + SH + epilogue ====================
__global__ __launch_bounds__(256) void nerf_mlp(
    const unsigned* __restrict__ enc,
    const float* __restrict__ dvec,
    const int*   __restrict__ app_idx,
    const float* __restrict__ app_table,
    const float* __restrict__ sw0, const float* __restrict__ sb0,
    const float* __restrict__ sw1, const float* __restrict__ sb1,
    const float* __restrict__ cw0, const float* __restrict__ cb0,
    const float* __restrict__ cw1, const float* __restrict__ cb1,
    const float* __restrict__ cw2, const float* __restrict__ cb2,
    float* __restrict__ out, int p0, int P, int n_pts)
{
    int p = blockIdx.x * blockDim.x + threadIdx.x;
    if (p >= P) return;
    int n = p0 + p;
    if (n >= n_pts) return;

    // ---- density layer 0 from packed enc ----
    float h[HID];
    #pragma unroll
    for (int o = 0; o < HID; o++) h[o] = sb0[o];
    const unsigned* ep = enc + p;
    #pragma unroll
    for (int l = 0; l < NL; l++) {
        unsigned u = ep[(size_t)l * P];
        float e0, e1;
        corner_vals(u, e0, e1);
        const float* r0 = sw0 + (2 * l) * HID;
        #pragma unroll
        for (int o = 0; o < HID; o++) h[o] += e0 * r0[o] + e1 * r0[HID + o];
    }
    #pragma unroll
    for (int o = 0; o < HID; o++) h[o] = fmaxf(h[o], 0.f);

    float h1[16];
    #pragma unroll
    for (int o = 0; o < 16; o++) h1[o] = sb1[o];
    #pragma unroll
    for (int i = 0; i < HID; i++) {
        float v = h[i];
        const float* wr = sw1 + i * 16;
        #pragma unroll
        for (int o = 0; o < 16; o++) h1[o] += v * wr[o];
    }

    float z100 = 100.f * h1[0];
    float sigma = (z100 > 20.f) ? h1[0] : (log1pf(expf(z100)) * 0.01f);

    // ---- SH16 ----
    float dx = dvec[3*n+0], dy = dvec[3*n+1], dz = dvec[3*n+2];
    float invn = 1.0f / sqrtf(dx*dx + dy*dy + dz*dz);
    dx *= invn; dy *= invn; dz *= invn;
    float xx = dx*dx, yy = dy*dy, zz = dz*dz;
    float xy = dx*dy, yz = dy*dz, xz = dx*dz;
    float sh[16];
    sh[0]  = 0.28209479177387814f;
    sh[1]  = -0.48860251190291987f * dy;
    sh[2]  =  0.48860251190291987f * dz;
    sh[3]  = -0.48860251190291987f * dx;
    sh[4]  =  1.0925484305920792f * xy;
    sh[5]  = -1.0925484305920792f * yz;
    sh[6]  =  0.94617469575756f * zz - 0.31539156525252005f;
    sh[7]  = -1.0925484305920792f * xz;
    sh[8]  =  0.5462742152960396f * (xx - yy);
    sh[9]  = -0.5900435899266435f * dy * (3.f * xx - yy);
    sh[10] =  2.890611442640554f * xy * dz;
    sh[11] = -0.4570457994644657f * dy * (4.f * zz - xx - yy);
    sh[12] =  0.37317633259011546f * dz * (2.f * zz - 3.f * xx - 3.f * yy);
    sh[13] = -0.4570457994644657f * dx * (4.f * zz - xx - yy);
    sh[14] =  1.445305721320277f * dz * (xx - yy);
    sh[15] = -0.5900435899266435f * dx * (xx - 3.f * yy);

    // ---- color MLP ----
    float c1[HID];
    #pragma unroll
    for (int o = 0; o < HID; o++) c1[o] = cb0[o];
    #pragma unroll
    for (int i = 0; i < 15; i++) {
        float v = h1[i + 1];
        const float* wr = cw0 + i * HID;
        #pragma unroll
        for (int o = 0; o < HID; o++) c1[o] += v * wr[o];
    }
    #pragma unroll
    for (int i = 0; i < 16; i++) {
        float v = sh[i];
        const float* wr = cw0 + (15 + i) * HID;
        #pragma unroll
        for (int o = 0; o < HID; o++) c1[o] += v * wr[o];
    }
    {
        const float4* arow = reinterpret_cast<const float4*>(app_table + (size_t)app_idx[n] * 48);
        for (int j4 = 0; j4 < 12; j4++) {
            float4 v = arow[j4];
            const float* wr = cw0 + (31 + 4 * j4) * HID;
            #pragma unroll
            for (int o = 0; o < HID; o++) c1[o] += v.x * wr[o];
            #pragma unroll
            for (int o = 0; o < HID; o++) c1[o] += v.y * wr[HID + o];
            #pragma unroll
            for (int o = 0; o < HID; o++) c1[o] += v.z * wr[2 * HID + o];
            #pragma unroll
            for (int o = 0; o < HID; o++) c1[o] += v.w * wr[3 * HID + o];
        }
    }
    #pragma unroll
    for (int o = 0; o < HID; o++) c1[o] = fmaxf(c1[o], 0.f);

    float c2[HID];
    #pragma unroll
    for (int o = 0; o < HID; o++) c2[o] = cb1[o];
    #pragma unroll
    for (int i = 0; i < HID; i++) {
        float v = c1[i];
        const float* wr = cw1 + i * HID;
        #pragma unroll
        for (int o = 0; o < HID; o++) c2[o] += v * wr[o];
    }
    #pragma unroll
    for (int o = 0; o < HID; o++) c2[o] = fmaxf(c2[o], 0.f);

    float r = cb2[0], g = cb2[1], b = cb2[2];
    #pragma unroll
    for (int i = 0; i < HID; i++) {
        float v = c2[i];
        r += v * cw2[i * 3 + 0];
        g += v * cw2[i * 3 + 1];
        b += v * cw2[i * 3 + 2];
    }
    r = 1.f / (1.f + expf(-r));
    g = 1.f / (1.f + expf(-g));
    b = 1.f / (1.f + expf(-b));

    reinterpret_cast<float4*>(out)[n] = make_float4(sigma, r, g, b);
}

// ======================= Fused fallback (round-3 kernel) ===================
template <int USE_BF16>
__global__ __launch_bounds__(256) void nerf_fused(
    const float* __restrict__ x,
    const float* __restrict__ dvec,
    const int*   __restrict__ app_idx,
    const void*  __restrict__ tbl_raw,
    const float* __restrict__ app_table,
    const float* __restrict__ sw0, const float* __restrict__ sb0,
    const float* __restrict__ sw1, const float* __restrict__ sb1,
    const float* __restrict__ cw0, const float* __restrict__ cb0,
    const float* __restrict__ cw1, const float* __restrict__ cb1,
    const float* __restrict__ cw2, const float* __restrict__ cb2,
    float* __restrict__ out, Res16 rt, int n_pts)
{
    using CT = typename std::conditional<USE_BF16 != 0, unsigned, float2>::type;
    const CT* __restrict__ tbl = (const CT*)tbl_raw;

    int n = blockIdx.x * blockDim.x + threadIdx.x;
    if (n >= n_pts) return;

    float px = (x[3*n+0] + 1.f) * 0.5f;
    float py = (x[3*n+1] + 1.f) * 0.5f;
    float pz = (x[3*n+2] + 1.f) * 0.5f;

    float e[2*NL];
    #pragma unroll
    for (int l = 0; l < NL; l++) {
        float res = rt.r[l];
        float xs = px*res, ys = py*res, zs = pz*res;
        float fx = floorf(xs), fy = floorf(ys), fz = floorf(zs);
        float wx = xs - fx, wy = ys - fy, wz = zs - fz;
        float ax = 1.f - wx, ay = 1.f - wy, az = 1.f - wz;
        unsigned X = (unsigned)fx, Y = (unsigned)fy, Z = (unsigned)fz;
        unsigned hx0 = X,               hx1 = X + 1u;
        unsigned hy0 = Y * 2654435761u, hy1 = hy0 + 2654435761u;
        unsigned hz0 = Z * 805459861u,  hz1 = hz0 + 805459861u;
        const CT* base = tbl + (size_t)l * TBL_N;
        float e0 = 0.f, e1 = 0.f;
        #pragma unroll
        for (int c = 0; c < 8; c++) {
            unsigned idx = (((c & 4) ? hx1 : hx0) ^
                            ((c & 2) ? hy1 : hy0) ^
                            ((c & 1) ? hz1 : hz0)) & (TBL_N - 1u);
            CT v = base[idx];
            float f0, f1;
            corner_vals(v, f0, f1);
            float wgt = ((c & 4) ? wx : ax) * ((c & 2) ? wy : ay) * ((c & 1) ? wz : az);
            e0 += wgt * f0;
            e1 += wgt * f1;
        }
        e[2*l] = e0; e[2*l+1] = e1;
    }

    float h[HID];
    #pragma unroll
    for (int o = 0; o < HID; o++) h[o] = sb0[o];
    #pragma unroll
    for (int l = 0; l < NL; l++) {
        const float* r0 = sw0 + (2 * l) * HID;
        float e0 = e[2*l], e1 = e[2*l+1];
        #pragma unroll
        for (int o = 0; o < HID; o++) h[o] += e0 * r0[o] + e1 * r0[HID + o];
    }
    #pragma unroll
    for (int o = 0; o < HID; o++) h[o] = fmaxf(h[o], 0.f);

    float h1[16];
    #pragma unroll
    for (int o = 0; o < 16; o++) h1[o] = sb1[o];
    #pragma unroll
    for (int i = 0; i < HID; i++) {
        float v = h[i];
        const float* wr = sw1 + i * 16;
        #pragma unroll
        for (int o = 0; o < 16; o++) h1[o] += v * wr[o];
    }

    float z100 = 100.f * h1[0];
    float sigma = (z100 > 20.f) ? h1[0] : (log1pf(expf(z100)) * 0.01f);

    float dx = dvec[3*n+0], dy = dvec[3*n+1], dz = dvec[3*n+2];
    float invn = 1.0f / sqrtf(dx*dx + dy*dy + dz*dz);
    dx *= invn; dy *= invn; dz *= invn;
    float xx = dx*dx, yy = dy*dy, zz = dz*dz;
    float xy = dx*dy, yz = dy*dz, xz = dx*dz;
    float sh[16];
    sh[0]  = 0.28209479177387814f;
    sh[1]  = -0.48860251190291987f * dy;
    sh[2]  =  0.48860251190291987f * dz;
    sh[3]  = -0.48860251190291987f * dx;
    sh[4]  =  1.0925484305920792f * xy;
    sh[5]  = -1.0925484305920792f * yz;
    sh[6]  =  0.94617469575756f * zz - 0.31539156525252005f;
    sh[7]  = -1.0925484305920792f * xz;
    sh[8]  =  0.5462742152960396f * (xx - yy);
    sh[9]  = -0.5900435899266435f * dy * (3.f * xx - yy);
    sh[10] =  2.890611442640554f * xy * dz;
    sh[11] = -0.4570457994644657f * dy * (4.f * zz - xx - yy);
    sh[12] =  0.37317633259011546f * dz * (2.f * zz - 3.f * xx - 3.f * yy);
    sh[13] = -0.4570457994644657f * dx * (4.f * zz - xx - yy);
    sh[14] =  1.445305721320277f * dz * (xx - yy);
    sh[15] = -0.5900435899266435f * dx * (xx - 3.f * yy);

    float c1[HID];
    #pragma unroll
    for (int o = 0; o < HID; o++) c1[o] = cb0[o];
    #pragma unroll
    for (int i = 0; i < 15; i++) {
        float v = h1[i + 1];
        const float* wr = cw0 + i * HID;
        #pragma unroll
        for (int o = 0; o < HID; o++) c1[o] += v * wr[o];
    }
    #pragma unroll
    for (int i = 0; i < 16; i++) {
        float v = sh[i];
        const float* wr = cw0 + (15 + i) * HID;
        #pragma unroll
        for (int o = 0; o < HID; o++) c1[o] += v * wr[o];
    }
    {
        const float4* arow = reinterpret_cast<const float4*>(app_table + (size_t)app_idx[n] * 48);
        for (int j4 = 0; j4 < 12; j4++) {
            float4 v = arow[j4];
            const float* wr = cw0 + (31 + 4 * j4) * HID;
            #pragma unroll
            for (int o = 0; o < HID; o++) c1[o] += v.x * wr[o];
            #pragma unroll
            for (int o = 0; o < HID; o++) c1[o] += v.y * wr[HID + o];
            #pragma unroll
            for (int o = 0; o < HID; o++) c1[o] += v.z * wr[2 * HID + o];
            #pragma unroll
            for (int o = 0; o < HID; o++) c1[o] += v.w * wr[3 * HID + o];
        }
    }
    #pragma unroll
    for (int o = 0; o < HID; o++) c1[o] = fmaxf(c1[o], 0.f);

    float c2[HID];
    #pragma unroll
    for (int o = 0; o < HID; o++) c2[o] = cb1[o];
    #pragma unroll
    for (int i = 0; i < HID; i++) {
        float v = c1[i];
        const float* wr = cw1 + i * HID;
        #pragma unroll
        for (int o = 0; o < HID; o++) c2[o] += v * wr[o];
    }
    #pragma unroll
    for (int o = 0; o < HID; o++) c2[o] = fmaxf(c2[o], 0.f);

    float r = cb2[0], g = cb2[1], b = cb2[2];
    #pragma unroll
    for (int i = 0; i < HID; i++) {
        float v = c2[i];
        r += v * cw2[i * 3 + 0];
        g += v * cw2[i * 3 + 1];
        b += v * cw2[i * 3 + 2];
    }
    r = 1.f / (1.f + expf(-r));
    g = 1.f / (1.f + expf(-g));
    b = 1.f / (1.f + expf(-b));

    reinterpret_cast<float4*>(out)[n] = make_float4(sigma, r, g, b);
}

extern "C" void kernel_launch(void* const* d_in, const int* in_sizes, int n_in,
                              void* d_out, int out_size, void* d_ws, size_t ws_size,
                              hipStream_t stream) {
    const float* x         = (const float*)d_in[0];
    const float* dvec      = (const float*)d_in[1];
    const int*   app_idx   = (const int*)  d_in[2];
    const float* ht        = (const float*)d_in[3];
    const float* app_table = (const float*)d_in[4];
    const float* sw0 = (const float*)d_in[5];
    const float* sb0 = (const float*)d_in[6];
    const float* sw1 = (const float*)d_in[7];
    const float* sb1 = (const float*)d_in[8];
    const float* cw0 = (const float*)d_in[9];
    const float* cb0 = (const float*)d_in[10];
    const float* cw1 = (const float*)d_in[11];
    const float* cb1 = (const float*)d_in[12];
    const float* cw2 = (const float*)d_in[13];
    const float* cb2 = (const float*)d_in[14];

    int n_pts = in_sizes[0] / 3;

    Res16 rt;
    double bb = exp(log(2048.0 / 16.0) / 15.0);
    for (int l = 0; l < NL; l++) rt.r[l] = (float)floor(16.0 * pow(bb, (double)l));

    const size_t tbl_entries = (size_t)NL * TBL_N;
    const size_t tbl_bytes = tbl_entries * sizeof(unsigned);       // 32 MiB

    if (ws_size >= tbl_bytes + (4u << 20)) {
        // --- split path: bf16 table + chunked encode/MLP through free ws ---
        int nent = (int)tbl_entries;
        hipLaunchKernelGGL(repack_bf16, dim3((nent + 255) / 256), dim3(256), 0, stream,
                           (const float2*)ht, (unsigned*)d_ws, nent);

        size_t cap = (ws_size - tbl_bytes) / (NL * sizeof(unsigned));  // points per chunk
        if (cap > (size_t)n_pts) cap = (size_t)n_pts;
        cap &= ~(size_t)255;
        unsigned* enc = (unsigned*)((char*)d_ws + tbl_bytes);

        for (long p0 = 0; p0 < (long)n_pts; p0 += (long)cap) {
            int P = (int)(((long)n_pts - p0) < (long)cap ? ((long)n_pts - p0) : (long)cap);
            dim3 g((P + 255) / 256), blk(256);
            hipLaunchKernelGGL(nerf_encode, g, blk, 0, stream,
                               x, (const unsigned*)d_ws, enc, rt, (int)p0, P, n_pts);
            hipLaunchKernelGGL(nerf_mlp, g, blk, 0, stream,
                               enc, dvec, app_idx, app_table,
                               sw0, sb0, sw1, sb1, cw0, cb0, cw1, cb1, cw2, cb2,
                               (float*)d_out, (int)p0, P, n_pts);
        }
    } else if (ws_size >= tbl_bytes) {
        int nent = (int)tbl_entries;
        hipLaunchKernelGGL(repack_bf16, dim3((nent + 255) / 256), dim3(256), 0, stream,
                           (const float2*)ht, (unsigned*)d_ws, nent);
        dim3 g((n_pts + 255) / 256), blk(256);
        hipLaunchKernelGGL((nerf_fused<1>), g, blk, 0, stream,
                           x, dvec, app_idx, (const void*)d_ws, app_table,
                           sw0, sb0, sw1, sb1, cw0, cb0, cw1, cb1, cw2, cb2,
                           (float*)d_out, rt, n_pts);
    } else {
        dim3 g((n_pts + 255) / 256), blk(256);
        hipLaunchKernelGGL((nerf_fused<0>), g, blk, 0, stream,
                           x, dvec, app_idx, (const void*)ht, app_table,
                           sw0, sb0, sw1, sb1, cw0, cb0, cw1, cb1, cw2, cb2,
                           (float*)d_out, rt, n_pts);
    }
}